// Round 10
// baseline (37.521 us; speedup 1.0000x reference)
//
#include <hip/hip_runtime.h>

// SubtitleColorConsistencyLoss — MI355X (gfx950)
// R9: R8 + merged two-span fast path. Each group owns 2 spans; both slabs
//     checked up front; common case processes 32 independent loads + two
//     parallel reduce chains in ONE basic block so the scheduler can pipeline
//     span1 loads under span0's shuffle chain (static trip count, no
//     runtime-stride loop). Atomic-cliff lessons (R3/R4/R6) respected.

namespace {
constexpr int NIMG = 8;
constexpr int NCH  = 16;
constexpr int HWPX = 512 * 512;
constexpr int KSEG = 65;                 // labels 0..64; slot 0 = background
constexpr int NF   = 18;                 // [0]=count [1]=sqsum [2..17]=sums
constexpr int SPANS = HWPX / 64;         // 4096 spans per image
constexpr int TABF  = NIMG * KSEG * NF;  // 9360 floats
constexpr int NBLK  = 128;               // accum blocks per image
constexpr int HALF  = NBLK * 1024;       // 131072 px: offset of 2nd span set
// ws layout: [0, NIMG*SPANS) spanlab ints | [WS_TAB, +TABF) global table
constexpr int WS_TAB = NIMG * SPANS;     // 32768
constexpr float EPSV   = 1e-6f;
constexpr float MARGIN = 0.5f;
constexpr float LAMBDA = 0.4f;
constexpr float MINPIX = 20.0f;
}

// Pass A: span-label compression (uniform 64-px span -> label, else -1)
//         + zero the global table (image-0 blocks, plain stores).
__global__ __launch_bounds__(256) void spanlab_kernel(
    const int* __restrict__ labels, int* __restrict__ spanlab,
    float* __restrict__ tab)
{
    const int n   = blockIdx.y;
    const int tid = threadIdx.x;
    const int grp = tid >> 4, l16 = tid & 15, wgrp = (tid & 63) >> 4;
    const int span = blockIdx.x * 16 + grp;
    const int p    = span * 64 + l16 * 4;

    if (n == 0 && tid < 37) {
        const int idx = blockIdx.x * 37 + tid;
        if (idx < TABF) tab[idx] = 0.0f;
    }

    const int4 lab = *reinterpret_cast<const int4*>(labels + (size_t)n * HWPX + p);
    const int  lab0 = __shfl(lab.x, 0, 16);
    const bool uni  = (lab.x == lab.y) && (lab.x == lab.z) &&
                      (lab.x == lab.w) && (lab.x == lab0);
    const unsigned long long b = __ballot((int)uni);
    const unsigned long long m = 0xFFFFull << (wgrp * 16);
    if (l16 == 0)
        spanlab[n * SPANS + span] = ((b & m) == m) ? lab0 : -1;
}

__device__ __forceinline__ float hsum4(const float4 v) {
    return (v.x + v.y) + (v.z + v.w);
}
__device__ __forceinline__ float dot4(const float4 v) {
    return v.x * v.x + v.y * v.y + v.z * v.z + v.w * v.w;
}
// reduce-scatter over a 16-lane group: lane l ends owning channel l's total
__device__ __forceinline__ float rscatter16(float fs[NCH], const int l16) {
    #pragma unroll
    for (int c = 0; c < 8; ++c) {
        const float snd = (l16 & 8) ? fs[c] : fs[c + 8];
        const float kp  = (l16 & 8) ? fs[c + 8] : fs[c];
        fs[c] = kp + __shfl_xor(snd, 8, 16);
    }
    #pragma unroll
    for (int c = 0; c < 4; ++c) {
        const float snd = (l16 & 4) ? fs[c] : fs[c + 4];
        const float kp  = (l16 & 4) ? fs[c + 4] : fs[c];
        fs[c] = kp + __shfl_xor(snd, 4, 16);
    }
    #pragma unroll
    for (int c = 0; c < 2; ++c) {
        const float snd = (l16 & 2) ? fs[c] : fs[c + 2];
        const float kp  = (l16 & 2) ? fs[c + 2] : fs[c];
        fs[c] = kp + __shfl_xor(snd, 2, 16);
    }
    const float snd = (l16 & 1) ? fs[0] : fs[1];
    const float kp  = (l16 & 1) ? fs[1] : fs[0];
    return kp + __shfl_xor(snd, 1, 16);
}
__device__ __forceinline__ float wsum16(float x) {
    x += __shfl_xor(x, 8, 16);
    x += __shfl_xor(x, 4, 16);
    x += __shfl_xor(x, 2, 16);
    x += __shfl_xor(x, 1, 16);
    return x;
}

__device__ __forceinline__ void span_fast(
    const float* __restrict__ colN, float* __restrict__ ltab,
    const int p, const int slab, const int l16)
{
    float fs[NCH];
    float sq = 0.0f;
    #pragma unroll
    for (int c = 0; c < NCH; ++c) {
        const float4 v = *reinterpret_cast<const float4*>(
            colN + (size_t)c * HWPX + p);
        fs[c] = hsum4(v);
        sq += dot4(v);
    }
    const float own = rscatter16(fs, l16);
    sq = wsum16(sq);
    float* seg = ltab + slab * NF;
    atomicAdd(seg + 2 + l16, own);
    if (l16 == 0) {
        atomicAdd(seg + 0, 64.0f);
        atomicAdd(seg + 1, sq);
    }
}

__device__ __forceinline__ void span_fallback(
    const float* __restrict__ colN, const int* __restrict__ labN,
    float* __restrict__ ltab, const int p)
{
    const int4 lb = *reinterpret_cast<const int4*>(labN + p);
    const int labv[4] = {lb.x, lb.y, lb.z, lb.w};
    for (int i = 0; i < 4; ++i) {
        float sqp = 0.0f;
        float* seg = ltab + labv[i] * NF;
        for (int c = 0; c < NCH; ++c) {
            const float x = colN[(size_t)c * HWPX + p + i];
            sqp += x * x;
            atomicAdd(seg + 2 + c, x);
        }
        atomicAdd(seg + 0, 1.0f);
        atomicAdd(seg + 1, sqp);
    }
}

__global__ __launch_bounds__(256) void accum_kernel(
    const float* __restrict__ color,
    const int*   __restrict__ labels,
    const int*   __restrict__ spanlab,
    float* __restrict__ tab)
{
    __shared__ float ltab[KSEG * NF];
    const int tid = threadIdx.x;
    for (int i = tid; i < KSEG * NF; i += 256) ltab[i] = 0.0f;
    __syncthreads();

    const int n = blockIdx.y;
    const float* colN = color  + (size_t)n * NCH * HWPX;
    const int*   labN = labels + (size_t)n * HWPX;
    const int*   slN  = spanlab + n * SPANS;

    const int grp = tid >> 4;
    const int l16 = tid & 15;

    const int base0 = blockIdx.x * 1024;
    const int base1 = base0 + HALF;
    const int p0 = base0 + grp * 64 + l16 * 4;
    const int p1 = base1 + grp * 64 + l16 * 4;
    const int slab0 = slN[(base0 >> 6) + grp];
    const int slab1 = slN[(base1 >> 6) + grp];

    if ((slab0 | slab1) >= 0) {
        // merged fast path: 32 independent loads + two parallel reduce
        // chains in one basic block -> scheduler pipelines them.
        float fs0[NCH], fs1[NCH];
        float sq0 = 0.0f, sq1 = 0.0f;
        #pragma unroll
        for (int c = 0; c < NCH; ++c) {
            const float* cp = colN + (size_t)c * HWPX;
            const float4 v0 = *reinterpret_cast<const float4*>(cp + p0);
            const float4 v1 = *reinterpret_cast<const float4*>(cp + p1);
            fs0[c] = hsum4(v0);  sq0 += dot4(v0);
            fs1[c] = hsum4(v1);  sq1 += dot4(v1);
        }
        const float own0 = rscatter16(fs0, l16);
        const float own1 = rscatter16(fs1, l16);
        sq0 = wsum16(sq0);
        sq1 = wsum16(sq1);

        float* seg0 = ltab + slab0 * NF;
        float* seg1 = ltab + slab1 * NF;
        atomicAdd(seg0 + 2 + l16, own0);
        atomicAdd(seg1 + 2 + l16, own1);
        if (l16 == 0) {
            atomicAdd(seg0 + 0, 64.0f);
            atomicAdd(seg0 + 1, sq0);
            atomicAdd(seg1 + 0, 64.0f);
            atomicAdd(seg1 + 1, sq1);
        }
    } else {
        // rare: handle each span individually (fast or per-pixel fallback)
        if (slab0 >= 0) span_fast(colN, ltab, p0, slab0, l16);
        else            span_fallback(colN, labN, ltab, p0);
        if (slab1 >= 0) span_fast(colN, ltab, p1, slab1, l16);
        else            span_fallback(colN, labN, ltab, p1);
    }

    __syncthreads();
    float* tabN = tab + (size_t)n * KSEG * NF;
    for (int i = tid; i < KSEG * NF; i += 256) {
        const float x = ltab[i];
        if (x != 0.0f) atomicAdd(tabN + i, x);
    }
}

__global__ __launch_bounds__(256) void finalize_kernel(
    const float* __restrict__ tab, float* __restrict__ out)
{
    __shared__ float mbg[NIMG][NCH];
    __shared__ float bgcnt[NIMG];
    __shared__ float r0[256], r1[256], r2[256];
    const int tid = threadIdx.x;
    if (tid < NIMG * NCH) {
        const int n = tid / NCH, c = tid % NCH;
        const float* b = tab + (size_t)n * KSEG * NF;   // slot 0 = background
        const float cnt = b[0];
        mbg[n][c] = b[2 + c] / (cnt + EPSV);
        if (c == 0) bgcnt[n] = cnt;
    }
    __syncthreads();

    float vsum = 0.0f, intraS = 0.0f, interS = 0.0f;
    for (int idx = tid; idx < NIMG * KSEG; idx += 256) {
        const int n = idx / KSEG, k = idx % KSEG;
        if (k == 0) continue;
        const float* s = tab + ((size_t)n * KSEG + k) * NF;
        const float cnt = s[0], sq = s[1];
        const float denom = cnt + EPSV;
        float d2 = 0.0f, msf = 0.0f, msm = 0.0f;
        #pragma unroll
        for (int c = 0; c < NCH; ++c) {
            const float f  = s[2 + c];
            const float mu = f / denom;
            msf += mu * f;
            msm += mu * mu;
            const float dd = mu - mbg[n][c];
            d2 += dd * dd;
        }
        const float intra = (sq - 2.0f * msf + cnt * msm) / denom;
        const float dist  = sqrtf(d2 + 1e-12f);
        const float t     = fmaxf(MARGIN - dist, 0.0f);
        const float inter = t * t;
        if ((cnt >= MINPIX) && (bgcnt[n] >= MINPIX)) {
            vsum += 1.0f; intraS += intra; interS += inter;
        }
    }
    r0[tid] = vsum; r1[tid] = intraS; r2[tid] = interS;
    __syncthreads();
    for (int sft = 128; sft; sft >>= 1) {
        if (tid < sft) {
            r0[tid] += r0[tid + sft];
            r1[tid] += r1[tid + sft];
            r2[tid] += r2[tid + sft];
        }
        __syncthreads();
    }
    if (tid == 0) {
        const float total = r0[0];
        const float safe  = fmaxf(total, 1.0f);
        out[0] = (total > 0.0f) ? (r1[0] + LAMBDA * r2[0]) / safe : 0.0f;
    }
}

extern "C" void kernel_launch(void* const* d_in, const int* in_sizes, int n_in,
                              void* d_out, int out_size, void* d_ws, size_t ws_size,
                              hipStream_t stream) {
    const float* color  = (const float*)d_in[0];
    const int*   labels = (const int*)d_in[2];
    float* ws  = (float*)d_ws;
    float* out = (float*)d_out;

    int*   spanlab = (int*)ws;
    float* tab     = ws + WS_TAB;

    dim3 gridA(SPANS / 16, NIMG);    // 256 x 8 blocks; also zeroes tab
    spanlab_kernel<<<gridA, 256, 0, stream>>>(labels, spanlab, tab);

    dim3 gridB(NBLK, NIMG);          // 1024 blocks, 2 spans per group, merged
    accum_kernel<<<gridB, 256, 0, stream>>>(color, labels, spanlab, tab);

    finalize_kernel<<<1, 256, 0, stream>>>(tab, out);
}